// Round 2
// baseline (201.340 us; speedup 1.0000x reference)
//
#include <hip/hip_runtime.h>

// Problem constants (fixed by setup_inputs)
constexpr int BATCH = 8;
constexpr int NPB   = 1 << 20;       // N per batch
constexpr int BS    = 128;           // block_size
constexpr int NB    = NPB / BS;      // 8192 node-blocks per batch
constexpr int NBLK  = BATCH * NB;    // 65536 total node-blocks
constexpr int MAXKV = 32;

#define GRAPH_WEIGHT 0.3f

// Workspace layout (floats):
//  [0, 512)       : sup partials, 64 slots x 8 floats (+0 sup_sum, +1 sup_cnt)
//  [512, 1536)    : graph partials, 8 batches x 16 slots x 8 floats
//                   (+0 loss, +1 count, +2 uncertain_cnt)
//  [0, 2048)      : zeroed via hipMemsetAsync each call
//  WS_BSC         : float2[NBLK]  {sum keep*p, keep count}      (phase1 -> phase2 gather)
//  WS_QUP         : float4[NBLK]  {q, sum u*p, sum u*p^2, pad}
constexpr int WS_SUP   = 0;
constexpr int WS_GRAPH = 512;
constexpr int WS_ZERO  = 2048;                  // floats to zero
constexpr int WS_BSC   = 2048;                  // 2*NBLK floats
constexpr int WS_QUP   = WS_BSC + 2 * NBLK;     // 4*NBLK floats

// ---------------- Phase 1: per-element pass + per-block stats ----------------
// 16 elements/thread. One wave = 1024 elements = 8 node-blocks; lanes 8g..8g+7
// own block g, so block stats reduce in 3 xor stages. Per-instruction access
// pattern: 8 segments x 128B (full cache lines).
__global__ __launch_bounds__(256) void k_phase1(const float4* __restrict__ lg4,
                                                const float4* __restrict__ tg4,
                                                const int4* __restrict__ sm4,
                                                const int4* __restrict__ im4,
                                                float* __restrict__ ws)
{
    const int lane = threadIdx.x & 63;
    const int wid  = (blockIdx.x << 2) + (threadIdx.x >> 6); // global wave id
    const int grp  = lane >> 3;                  // block within wave (0..7)
    const int sub  = lane & 7;                   // sub-lane within block group
    const int blk  = (wid << 3) + grp;           // node-block id (0..NBLK-1)
    const int c0   = (blk << 5) + sub;           // float4-chunk index (32/block)

    float sup_sum = 0.f, sup_cnt = 0.f;
    float bsum = 0.f, bcnt = 0.f, q = 0.f, up = 0.f, up2 = 0.f;

#pragma unroll
    for (int j = 0; j < 4; ++j) {
        const int c = c0 + (j << 3);
        const float4 x4 = lg4[c];
        const float4 t4 = tg4[c];
        const int4   s4 = sm4[c];
        const int4   g4 = im4[c];

        const float xs[4]  = {x4.x, x4.y, x4.z, x4.w};
        const float ts[4]  = {t4.x, t4.y, t4.z, t4.w};
        const int   ssv[4] = {s4.x, s4.y, s4.z, s4.w};
        const int   ggv[4] = {g4.x, g4.y, g4.z, g4.w};

#pragma unroll
        for (int k = 0; k < 4; ++k) {
            const float x = xs[k], t = ts[k];
            const bool s = (ssv[k] != 0);
            const bool g = (ggv[k] != 0);

            const float ax  = fabsf(x);
            const float e   = __expf(-ax);          // (0,1]
            const float lp  = __logf(1.f + e);      // log1p(exp(-|x|))
            const float per = fmaxf(x, 0.f) - x * t + lp;
            const float inv = 1.f / (1.f + e);
            const float p   = (x >= 0.f) ? inv : e * inv;   // sigmoid(x)

            if (s) { sup_sum += per; sup_cnt += 1.f; }
            if (!g) { bsum += p; bcnt += 1.f; }
            if (!g && !s) { q += 1.f; up += p; up2 += p * p; }
        }
    }

    // block stats: reduce over the 8-lane group (d = 1,2,4)
#pragma unroll
    for (int d = 4; d >= 1; d >>= 1) {
        bsum += __shfl_xor(bsum, d);
        bcnt += __shfl_xor(bcnt, d);
        q    += __shfl_xor(q, d);
        up   += __shfl_xor(up, d);
        up2  += __shfl_xor(up2, d);
    }
    if (sub == 0) {
        *reinterpret_cast<float2*>(ws + WS_BSC + 2 * blk) = make_float2(bsum, bcnt);
        *reinterpret_cast<float4*>(ws + WS_QUP + 4 * blk) = make_float4(q, up, up2, 0.f);
    }

    // sup terms: full-wave reduction
#pragma unroll
    for (int d = 32; d >= 1; d >>= 1) {
        sup_sum += __shfl_xor(sup_sum, d);
        sup_cnt += __shfl_xor(sup_cnt, d);
    }
    __shared__ float lds[4][2];
    const int w = threadIdx.x >> 6;
    if (lane == 0) { lds[w][0] = sup_sum; lds[w][1] = sup_cnt; }
    __syncthreads();
    if (threadIdx.x == 0) {
        const float a = lds[0][0] + lds[1][0] + lds[2][0] + lds[3][0];
        const float b = lds[0][1] + lds[1][1] + lds[2][1] + lds[3][1];
        float* slot = ws + WS_SUP + (int)(blockIdx.x & 63) * 8;  // 64-way striping
        atomicAdd(slot + 0, a);
        atomicAdd(slot + 1, b);
    }
}

// ---------------- Phase 2: neighbor gather per node-block ----------------
// One 32-lane half-wave per node-block; lane k handles neighbor k. Gather is a
// single 8B load from the L2-resident float2 table.
__global__ __launch_bounds__(256) void k_phase2(const int* __restrict__ kvi,
                                                const int* __restrict__ kvn,
                                                float* __restrict__ ws)
{
    const int tid    = blockIdx.x * 256 + threadIdx.x;
    const int h      = tid >> 5;            // node-block id
    const int lane32 = threadIdx.x & 31;
    const int b      = h >> 13;             // NB = 8192; 8 blocks/wg share batch

    const int nkv = kvn[h];
    const int idx = kvi[(size_t)h * MAXKV + lane32];

    float gs = 0.f, gc = 0.f;
    if (lane32 < nkv) {
        const int src = (h & ~(NB - 1)) + idx;   // b*NB + idx
        const float2 v = *reinterpret_cast<const float2*>(ws + WS_BSC + 2 * src);
        gs = v.x; gc = v.y;
    }
#pragma unroll
    for (int d = 16; d >= 1; d >>= 1) {
        gs += __shfl_xor(gs, d);
        gc += __shfl_xor(gc, d);
    }

    __shared__ float lds[8][3];
    if (lane32 == 0) {
        const float4 quv = *reinterpret_cast<const float4*>(ws + WS_QUP + 4 * h);
        const float q = quv.x, up = quv.y, up2 = quv.z;
        const float m  = gs / fmaxf(gc, 1.f);
        const bool  vb = (q > 0.f) && (nkv > 0) && (gc > 0.f);
        // sum_u (p - m)^2 = sum_u p^2 - 2 m sum_u p + m^2 q
        const float sq = up2 - 2.f * m * up + m * m * q;
        const int hw = threadIdx.x >> 5;
        lds[hw][0] = vb ? sq : 0.f;
        lds[hw][1] = vb ? q  : 0.f;
        lds[hw][2] = q;                      // unconditional: uncertain.any()
    }
    __syncthreads();
    if (threadIdx.x == 0) {
        float L = 0.f, C = 0.f, U = 0.f;
#pragma unroll
        for (int j = 0; j < 8; ++j) { L += lds[j][0]; C += lds[j][1]; U += lds[j][2]; }
        float* slot = ws + WS_GRAPH + b * 128 + (int)(blockIdx.x & 15) * 8;
        atomicAdd(slot + 0, L);
        atomicAdd(slot + 1, C);
        atomicAdd(slot + 2, U);
    }
}

// ---------------- Phase 3: final scalar ----------------
__global__ __launch_bounds__(64) void k_phase3(const float* __restrict__ ws,
                                               float* __restrict__ out)
{
    const int lane = threadIdx.x;  // 0..63

    float ss = ws[WS_SUP + lane * 8 + 0];
    float sc = ws[WS_SUP + lane * 8 + 1];
#pragma unroll
    for (int d = 32; d >= 1; d >>= 1) {
        ss += __shfl_xor(ss, d);
        sc += __shfl_xor(sc, d);
    }

    float per_sum = 0.f, nvalid = 0.f, uc = 0.f;
    for (int b = 0; b < BATCH; ++b) {
        float l = 0.f, c = 0.f, u = 0.f;
        if (lane < 16) {
            l = ws[WS_GRAPH + b * 128 + lane * 8 + 0];
            c = ws[WS_GRAPH + b * 128 + lane * 8 + 1];
            u = ws[WS_GRAPH + b * 128 + lane * 8 + 2];
        }
#pragma unroll
        for (int d = 32; d >= 1; d >>= 1) {
            l += __shfl_xor(l, d);
            c += __shfl_xor(c, d);
            u += __shfl_xor(u, d);
        }
        if (c > 0.f) { per_sum += l / fmaxf(c, 1.f); nvalid += 1.f; }
        uc += u;
    }

    if (lane == 0) {
        const float loss_sup = (sc > 0.f) ? ss / fmaxf(sc, 1.f) : 0.f;
        float lg = per_sum / fmaxf(nvalid, 1.f);
        if (!(uc > 0.f)) lg = 0.f;
        out[0] = loss_sup + GRAPH_WEIGHT * lg;
    }
}

extern "C" void kernel_launch(void* const* d_in, const int* in_sizes, int n_in,
                              void* d_out, int out_size, void* d_ws, size_t ws_size,
                              hipStream_t stream) {
    const float4* lg4 = (const float4*)d_in[0];  // logits  [B,N,1]
    const float4* tg4 = (const float4*)d_in[1];  // targets [B,N]
    const int4*   sm4 = (const int4*)d_in[2];    // sup_mask (int32)
    const int4*   im4 = (const int4*)d_in[3];    // ignore_mask (int32)
    const int*    kvi = (const int*)d_in[4];     // kv_indices [B,NB,MAXKV]
    const int*    kvn = (const int*)d_in[5];     // kv_num_blocks [B,NB]
    float* ws  = (float*)d_ws;
    float* out = (float*)d_out;

    hipMemsetAsync(d_ws, 0, WS_ZERO * sizeof(float), stream);

    // Phase 1: 8.39M elements, 16 per thread -> 2048 workgroups of 256
    k_phase1<<<(BATCH * NPB) / (16 * 256), 256, 0, stream>>>(lg4, tg4, sm4, im4, ws);
    // Phase 2: 65536 node-blocks, 32 lanes each -> 8192 workgroups of 256
    k_phase2<<<(NBLK * 32) / 256, 256, 0, stream>>>(kvi, kvn, ws);
    // Phase 3: single wave
    k_phase3<<<1, 64, 0, stream>>>(ws, out);
}

// Round 3
// 196.663 us; speedup vs baseline: 1.0238x; 1.0238x over previous
//
#include <hip/hip_runtime.h>

// Problem constants (fixed by setup_inputs)
constexpr int BATCH = 8;
constexpr int NPB   = 1 << 20;       // N per batch
constexpr int BS    = 128;           // block_size
constexpr int NB    = NPB / BS;      // 8192 node-blocks per batch
constexpr int NBLK  = BATCH * NB;    // 65536 total node-blocks
constexpr int MAXKV = 32;

#define GRAPH_WEIGHT 0.3f

// Workspace layout (floats):
//  [0, 512)       : sup partials, 64 slots x 8 floats (+0 sup_sum, +1 sup_cnt)
//  [512, 1536)    : graph partials, 8 batches x 16 slots x 8 floats
//                   (+0 loss, +1 count, +2 uncertain_cnt)
//  [0, 2048)      : zeroed via hipMemsetAsync each call
//  WS_BSC         : float2[NBLK]  {sum keep*p, keep count}      (phase1 -> phase2 gather)
//  WS_QUP         : float4[NBLK]  {q, sum u*p, sum u*p^2, pad}
constexpr int WS_SUP   = 0;
constexpr int WS_GRAPH = 512;
constexpr int WS_ZERO  = 2048;                  // floats to zero
constexpr int WS_BSC   = 2048;                  // 2*NBLK floats
constexpr int WS_QUP   = WS_BSC + 2 * NBLK;     // 4*NBLK floats

// ---------------- Phase 1: per-element pass + per-block stats ----------------
// 16 elements/thread. One wave = 1024 elements = 8 node-blocks; lanes 8g..8g+7
// own block g (3-stage xor reduction for block stats).
// KEY CHANGE vs R2: all 16 global loads are hoisted into registers BEFORE any
// compute, so each wave keeps 16KB of reads in flight back-to-back instead of
// draining its miss queue in 4-load bursts (measured wall: 2.85 TB/s ==
// ~32 lines/CU outstanding; this targets the 6.3 TB/s streaming ceiling).
__global__ __launch_bounds__(256) void k_phase1(const float4* __restrict__ lg4,
                                                const float4* __restrict__ tg4,
                                                const int4* __restrict__ sm4,
                                                const int4* __restrict__ im4,
                                                float* __restrict__ ws)
{
    const int lane = threadIdx.x & 63;
    const int wid  = (blockIdx.x << 2) + (threadIdx.x >> 6); // global wave id
    const int grp  = lane >> 3;                  // block within wave (0..7)
    const int sub  = lane & 7;                   // sub-lane within block group
    const int blk  = (wid << 3) + grp;           // node-block id (0..NBLK-1)
    const int c0   = (blk << 5) + sub;           // float4-chunk index (32/block)

    // ---- burst-issue all 16 loads (4 streams x 4 chunks) ----
    float4 xv[4], tv[4];
    int4   sv[4], gv[4];
#pragma unroll
    for (int j = 0; j < 4; ++j) xv[j] = lg4[c0 + (j << 3)];
#pragma unroll
    for (int j = 0; j < 4; ++j) tv[j] = tg4[c0 + (j << 3)];
#pragma unroll
    for (int j = 0; j < 4; ++j) sv[j] = sm4[c0 + (j << 3)];
#pragma unroll
    for (int j = 0; j < 4; ++j) gv[j] = im4[c0 + (j << 3)];

    float sup_sum = 0.f, sup_cnt = 0.f;
    float bsum = 0.f, bcnt = 0.f, q = 0.f, up = 0.f, up2 = 0.f;

#pragma unroll
    for (int j = 0; j < 4; ++j) {
        const float xs[4]  = {xv[j].x, xv[j].y, xv[j].z, xv[j].w};
        const float ts[4]  = {tv[j].x, tv[j].y, tv[j].z, tv[j].w};
        const int   ssv[4] = {sv[j].x, sv[j].y, sv[j].z, sv[j].w};
        const int   ggv[4] = {gv[j].x, gv[j].y, gv[j].z, gv[j].w};

#pragma unroll
        for (int k = 0; k < 4; ++k) {
            const float x = xs[k], t = ts[k];
            const bool s = (ssv[k] != 0);
            const bool g = (ggv[k] != 0);

            const float ax  = fabsf(x);
            const float e   = __expf(-ax);          // (0,1]
            const float lp  = __logf(1.f + e);      // log1p(exp(-|x|))
            const float per = fmaxf(x, 0.f) - x * t + lp;
            const float inv = 1.f / (1.f + e);
            const float p   = (x >= 0.f) ? inv : e * inv;   // sigmoid(x)

            if (s) { sup_sum += per; sup_cnt += 1.f; }
            if (!g) { bsum += p; bcnt += 1.f; }
            if (!g && !s) { q += 1.f; up += p; up2 += p * p; }
        }
    }

    // block stats: reduce over the 8-lane group (d = 4,2,1)
#pragma unroll
    for (int d = 4; d >= 1; d >>= 1) {
        bsum += __shfl_xor(bsum, d);
        bcnt += __shfl_xor(bcnt, d);
        q    += __shfl_xor(q, d);
        up   += __shfl_xor(up, d);
        up2  += __shfl_xor(up2, d);
    }
    if (sub == 0) {
        *reinterpret_cast<float2*>(ws + WS_BSC + 2 * blk) = make_float2(bsum, bcnt);
        *reinterpret_cast<float4*>(ws + WS_QUP + 4 * blk) = make_float4(q, up, up2, 0.f);
    }

    // sup terms: full-wave reduction
#pragma unroll
    for (int d = 32; d >= 1; d >>= 1) {
        sup_sum += __shfl_xor(sup_sum, d);
        sup_cnt += __shfl_xor(sup_cnt, d);
    }
    __shared__ float lds[4][2];
    const int w = threadIdx.x >> 6;
    if (lane == 0) { lds[w][0] = sup_sum; lds[w][1] = sup_cnt; }
    __syncthreads();
    if (threadIdx.x == 0) {
        const float a = lds[0][0] + lds[1][0] + lds[2][0] + lds[3][0];
        const float b = lds[0][1] + lds[1][1] + lds[2][1] + lds[3][1];
        float* slot = ws + WS_SUP + (int)(blockIdx.x & 63) * 8;  // 64-way striping
        atomicAdd(slot + 0, a);
        atomicAdd(slot + 1, b);
    }
}

// ---------------- Phase 2: neighbor gather per node-block ----------------
// One 32-lane half-wave per node-block; lane k handles neighbor k. Gather is a
// single 8B load from the L2-resident float2 table.
__global__ __launch_bounds__(256) void k_phase2(const int* __restrict__ kvi,
                                                const int* __restrict__ kvn,
                                                float* __restrict__ ws)
{
    const int tid    = blockIdx.x * 256 + threadIdx.x;
    const int h      = tid >> 5;            // node-block id
    const int lane32 = threadIdx.x & 31;
    const int b      = h >> 13;             // NB = 8192; 8 blocks/wg share batch

    const int nkv = kvn[h];
    const int idx = kvi[(size_t)h * MAXKV + lane32];

    float gs = 0.f, gc = 0.f;
    if (lane32 < nkv) {
        const int src = (h & ~(NB - 1)) + idx;   // b*NB + idx
        const float2 v = *reinterpret_cast<const float2*>(ws + WS_BSC + 2 * src);
        gs = v.x; gc = v.y;
    }
#pragma unroll
    for (int d = 16; d >= 1; d >>= 1) {
        gs += __shfl_xor(gs, d);
        gc += __shfl_xor(gc, d);
    }

    __shared__ float lds[8][3];
    if (lane32 == 0) {
        const float4 quv = *reinterpret_cast<const float4*>(ws + WS_QUP + 4 * h);
        const float q = quv.x, up = quv.y, up2 = quv.z;
        const float m  = gs / fmaxf(gc, 1.f);
        const bool  vb = (q > 0.f) && (nkv > 0) && (gc > 0.f);
        // sum_u (p - m)^2 = sum_u p^2 - 2 m sum_u p + m^2 q
        const float sq = up2 - 2.f * m * up + m * m * q;
        const int hw = threadIdx.x >> 5;
        lds[hw][0] = vb ? sq : 0.f;
        lds[hw][1] = vb ? q  : 0.f;
        lds[hw][2] = q;                      // unconditional: uncertain.any()
    }
    __syncthreads();
    if (threadIdx.x == 0) {
        float L = 0.f, C = 0.f, U = 0.f;
#pragma unroll
        for (int j = 0; j < 8; ++j) { L += lds[j][0]; C += lds[j][1]; U += lds[j][2]; }
        float* slot = ws + WS_GRAPH + b * 128 + (int)(blockIdx.x & 15) * 8;
        atomicAdd(slot + 0, L);
        atomicAdd(slot + 1, C);
        atomicAdd(slot + 2, U);
    }
}

// ---------------- Phase 3: final scalar ----------------
__global__ __launch_bounds__(64) void k_phase3(const float* __restrict__ ws,
                                               float* __restrict__ out)
{
    const int lane = threadIdx.x;  // 0..63

    float ss = ws[WS_SUP + lane * 8 + 0];
    float sc = ws[WS_SUP + lane * 8 + 1];
#pragma unroll
    for (int d = 32; d >= 1; d >>= 1) {
        ss += __shfl_xor(ss, d);
        sc += __shfl_xor(sc, d);
    }

    float per_sum = 0.f, nvalid = 0.f, uc = 0.f;
    for (int b = 0; b < BATCH; ++b) {
        float l = 0.f, c = 0.f, u = 0.f;
        if (lane < 16) {
            l = ws[WS_GRAPH + b * 128 + lane * 8 + 0];
            c = ws[WS_GRAPH + b * 128 + lane * 8 + 1];
            u = ws[WS_GRAPH + b * 128 + lane * 8 + 2];
        }
#pragma unroll
        for (int d = 32; d >= 1; d >>= 1) {
            l += __shfl_xor(l, d);
            c += __shfl_xor(c, d);
            u += __shfl_xor(u, d);
        }
        if (c > 0.f) { per_sum += l / fmaxf(c, 1.f); nvalid += 1.f; }
        uc += u;
    }

    if (lane == 0) {
        const float loss_sup = (sc > 0.f) ? ss / fmaxf(sc, 1.f) : 0.f;
        float lg = per_sum / fmaxf(nvalid, 1.f);
        if (!(uc > 0.f)) lg = 0.f;
        out[0] = loss_sup + GRAPH_WEIGHT * lg;
    }
}

extern "C" void kernel_launch(void* const* d_in, const int* in_sizes, int n_in,
                              void* d_out, int out_size, void* d_ws, size_t ws_size,
                              hipStream_t stream) {
    const float4* lg4 = (const float4*)d_in[0];  // logits  [B,N,1]
    const float4* tg4 = (const float4*)d_in[1];  // targets [B,N]
    const int4*   sm4 = (const int4*)d_in[2];    // sup_mask (int32)
    const int4*   im4 = (const int4*)d_in[3];    // ignore_mask (int32)
    const int*    kvi = (const int*)d_in[4];     // kv_indices [B,NB,MAXKV]
    const int*    kvn = (const int*)d_in[5];     // kv_num_blocks [B,NB]
    float* ws  = (float*)d_ws;
    float* out = (float*)d_out;

    hipMemsetAsync(d_ws, 0, WS_ZERO * sizeof(float), stream);

    // Phase 1: 8.39M elements, 16 per thread -> 2048 workgroups of 256
    k_phase1<<<(BATCH * NPB) / (16 * 256), 256, 0, stream>>>(lg4, tg4, sm4, im4, ws);
    // Phase 2: 65536 node-blocks, 32 lanes each -> 8192 workgroups of 256
    k_phase2<<<(NBLK * 32) / 256, 256, 0, stream>>>(kvi, kvn, ws);
    // Phase 3: single wave
    k_phase3<<<1, 64, 0, stream>>>(ws, out);
}

// Round 4
// 171.712 us; speedup vs baseline: 1.1725x; 1.1453x over previous
//
#include <hip/hip_runtime.h>

// Problem constants (fixed by setup_inputs)
constexpr int BATCH = 8;
constexpr int NPB   = 1 << 20;       // N per batch
constexpr int BS    = 128;           // block_size
constexpr int NB    = NPB / BS;      // 8192 node-blocks per batch
constexpr int NBLK  = BATCH * NB;    // 65536 total node-blocks
constexpr int MAXKV = 32;

#define GRAPH_WEIGHT 0.3f

constexpr int P1_WGS = (BATCH * NPB) / (256 * 8);  // 4096 workgroups, 8 elems/thread
constexpr int P2_WGS = NBLK / 8;                    // 8192 workgroups

// Workspace layout (floats). Every slot is fully overwritten each call ->
// NO memset dispatch, NO atomics anywhere.
constexpr int WS_BSC = 0;                    // float2[NBLK] {sum keep*p, keep cnt}
constexpr int WS_QUP = 2 * NBLK;             // float4[NBLK] {q, sum u*p, sum u*p^2, 0}
constexpr int WS_SUP = WS_QUP + 4 * NBLK;    // float2[P1_WGS] {sup_sum, sup_cnt}
constexpr int WS_P2  = WS_SUP + 2 * P1_WGS;  // float4[P2_WGS] {L, C, U, 0}

typedef float v4f __attribute__((ext_vector_type(4)));
typedef int   v4i __attribute__((ext_vector_type(4)));

// ---------------- Phase 1: per-element pass + per-block stats ----------------
// 8 elements/thread via NONTEMPORAL float4/int4 loads (data is read-once:
// bypass L1 so streamed misses don't consume the ~28-line/CU miss-tracking
// budget that has pinned this kernel at 2.85 TB/s across three variants).
// One wave = 512 elements = 4 node-blocks; lanes 16g..16g+15 own block g.
__global__ __launch_bounds__(256) void k_phase1(const v4f* __restrict__ lg4,
                                                const v4f* __restrict__ tg4,
                                                const v4i* __restrict__ sm4,
                                                const v4i* __restrict__ im4,
                                                float* __restrict__ ws)
{
    const int lane = threadIdx.x & 63;
    const int wid  = (blockIdx.x << 2) + (threadIdx.x >> 6); // global wave id
    const int grp  = lane >> 4;                  // block within wave (0..3)
    const int sub  = lane & 15;                  // sub-lane within block group
    const int blk  = (wid << 2) + grp;           // node-block id (0..NBLK-1)
    const int c0   = (blk << 5) + sub;           // float4-chunk index (32/block)

    v4f xv[2], tv[2];
    v4i sv[2], gv[2];
    xv[0] = __builtin_nontemporal_load(lg4 + c0);
    xv[1] = __builtin_nontemporal_load(lg4 + c0 + 16);
    tv[0] = __builtin_nontemporal_load(tg4 + c0);
    tv[1] = __builtin_nontemporal_load(tg4 + c0 + 16);
    sv[0] = __builtin_nontemporal_load(sm4 + c0);
    sv[1] = __builtin_nontemporal_load(sm4 + c0 + 16);
    gv[0] = __builtin_nontemporal_load(im4 + c0);
    gv[1] = __builtin_nontemporal_load(im4 + c0 + 16);

    float sup_sum = 0.f, sup_cnt = 0.f;
    float bsum = 0.f, bcnt = 0.f, q = 0.f, up = 0.f, up2 = 0.f;

#pragma unroll
    for (int j = 0; j < 2; ++j) {
#pragma unroll
        for (int k = 0; k < 4; ++k) {
            const float x = xv[j][k], t = tv[j][k];
            const bool s = (sv[j][k] != 0);
            const bool g = (gv[j][k] != 0);

            const float ax  = fabsf(x);
            const float e   = __expf(-ax);          // (0,1]
            const float lp  = __logf(1.f + e);      // log1p(exp(-|x|))
            const float per = fmaxf(x, 0.f) - x * t + lp;
            const float inv = 1.f / (1.f + e);
            const float p   = (x >= 0.f) ? inv : e * inv;   // sigmoid(x)

            if (s) { sup_sum += per; sup_cnt += 1.f; }
            if (!g) { bsum += p; bcnt += 1.f; }
            if (!g && !s) { q += 1.f; up += p; up2 += p * p; }
        }
    }

    // block stats: reduce over the 16-lane group (d = 8,4,2,1)
#pragma unroll
    for (int d = 8; d >= 1; d >>= 1) {
        bsum += __shfl_xor(bsum, d);
        bcnt += __shfl_xor(bcnt, d);
        q    += __shfl_xor(q, d);
        up   += __shfl_xor(up, d);
        up2  += __shfl_xor(up2, d);
    }
    if (sub == 0) {
        *reinterpret_cast<float2*>(ws + WS_BSC + 2 * blk) = make_float2(bsum, bcnt);
        *reinterpret_cast<float4*>(ws + WS_QUP + 4 * blk) = make_float4(q, up, up2, 0.f);
    }

    // sup terms: full-wave reduction, then ONE plain store per workgroup
#pragma unroll
    for (int d = 32; d >= 1; d >>= 1) {
        sup_sum += __shfl_xor(sup_sum, d);
        sup_cnt += __shfl_xor(sup_cnt, d);
    }
    __shared__ float lds[4][2];
    const int w = threadIdx.x >> 6;
    if (lane == 0) { lds[w][0] = sup_sum; lds[w][1] = sup_cnt; }
    __syncthreads();
    if (threadIdx.x == 0) {
        const float a = lds[0][0] + lds[1][0] + lds[2][0] + lds[3][0];
        const float b = lds[0][1] + lds[1][1] + lds[2][1] + lds[3][1];
        *reinterpret_cast<float2*>(ws + WS_SUP + 2 * blockIdx.x) = make_float2(a, b);
    }
}

// ---------------- Phase 2: neighbor gather per node-block ----------------
// One 32-lane half-wave per node-block; lane k handles neighbor k. Per-wg
// partial written to a unique float4 slot (no atomics).
__global__ __launch_bounds__(256) void k_phase2(const v4i* __restrict__ kvi4,
                                                const int* __restrict__ kvn,
                                                float* __restrict__ ws)
{
    const int tid    = blockIdx.x * 256 + threadIdx.x;
    const int h      = tid >> 5;            // node-block id
    const int lane32 = threadIdx.x & 31;

    const int nkv = kvn[h];
    // coalesced nontemporal read of kv_indices (8.4 MB, read-once)
    const v4i kq = __builtin_nontemporal_load(kvi4 + (h << 3) + (lane32 >> 2));
    const int idx = kq[lane32 & 3];

    float gs = 0.f, gc = 0.f;
    if (lane32 < nkv) {
        const int src = (h & ~(NB - 1)) + idx;   // b*NB + idx
        const float2 v = *reinterpret_cast<const float2*>(ws + WS_BSC + 2 * src);
        gs = v.x; gc = v.y;
    }
#pragma unroll
    for (int d = 16; d >= 1; d >>= 1) {
        gs += __shfl_xor(gs, d);
        gc += __shfl_xor(gc, d);
    }

    __shared__ float lds[8][3];
    if (lane32 == 0) {
        const float4 quv = *reinterpret_cast<const float4*>(ws + WS_QUP + 4 * h);
        const float q = quv.x, up = quv.y, up2 = quv.z;
        const float m  = gs / fmaxf(gc, 1.f);
        const bool  vb = (q > 0.f) && (nkv > 0) && (gc > 0.f);
        // sum_u (p - m)^2 = sum_u p^2 - 2 m sum_u p + m^2 q
        const float sq = up2 - 2.f * m * up + m * m * q;
        const int hw = threadIdx.x >> 5;
        lds[hw][0] = vb ? sq : 0.f;
        lds[hw][1] = vb ? q  : 0.f;
        lds[hw][2] = q;                      // unconditional: uncertain.any()
    }
    __syncthreads();
    if (threadIdx.x == 0) {
        float L = 0.f, C = 0.f, U = 0.f;
#pragma unroll
        for (int j = 0; j < 8; ++j) { L += lds[j][0]; C += lds[j][1]; U += lds[j][2]; }
        // wg id -> batch = blockIdx.x >> 10 (1024 wgs per batch, contiguous)
        *reinterpret_cast<float4*>(ws + WS_P2 + 4 * blockIdx.x) = make_float4(L, C, U, 0.f);
    }
}

// ---------------- Phase 3: final reduce (one 1024-thread workgroup) ----------
__global__ __launch_bounds__(1024) void k_phase3(const float* __restrict__ ws,
                                                 float* __restrict__ out)
{
    const int tid  = threadIdx.x;          // 0..1023
    const int lane = tid & 63;
    const int w    = tid >> 6;             // wave 0..15

    __shared__ float lsup[16][2];
    __shared__ float lb[8][16][3];
    __shared__ float lfin[8][3];

    // sup partials: 4096 float2 slots, 4 per thread
    float ss = 0.f, sc = 0.f;
#pragma unroll
    for (int j = 0; j < 4; ++j) {
        const float2 v = *reinterpret_cast<const float2*>(ws + WS_SUP + 2 * (tid + j * 1024));
        ss += v.x; sc += v.y;
    }
#pragma unroll
    for (int d = 32; d >= 1; d >>= 1) { ss += __shfl_xor(ss, d); sc += __shfl_xor(sc, d); }
    if (lane == 0) { lsup[w][0] = ss; lsup[w][1] = sc; }

    // graph partials: 8192 float4 slots, one per thread per batch
    float L[8], C[8], U[8];
#pragma unroll
    for (int b = 0; b < 8; ++b) {
        const float4 v = *reinterpret_cast<const float4*>(ws + WS_P2 + 4 * (b * 1024 + tid));
        L[b] = v.x; C[b] = v.y; U[b] = v.z;
    }
#pragma unroll
    for (int b = 0; b < 8; ++b) {
#pragma unroll
        for (int d = 32; d >= 1; d >>= 1) {
            L[b] += __shfl_xor(L[b], d);
            C[b] += __shfl_xor(C[b], d);
            U[b] += __shfl_xor(U[b], d);
        }
    }
    if (lane == 0) {
#pragma unroll
        for (int b = 0; b < 8; ++b) { lb[b][w][0] = L[b]; lb[b][w][1] = C[b]; lb[b][w][2] = U[b]; }
    }
    __syncthreads();

    // 128 threads (waves 0-1): 16-lane group per batch
    if (tid < 128) {
        const int b = tid >> 4, i = tid & 15;
        float l = lb[b][i][0], c = lb[b][i][1], u = lb[b][i][2];
#pragma unroll
        for (int d = 8; d >= 1; d >>= 1) {
            l += __shfl_xor(l, d);
            c += __shfl_xor(c, d);
            u += __shfl_xor(u, d);
        }
        if (i == 0) { lfin[b][0] = l; lfin[b][1] = c; lfin[b][2] = u; }
    }
    __syncthreads();

    if (tid == 0) {
        float ssum = 0.f, scn = 0.f;
#pragma unroll
        for (int j = 0; j < 16; ++j) { ssum += lsup[j][0]; scn += lsup[j][1]; }
        float per = 0.f, nv = 0.f, uc = 0.f;
#pragma unroll
        for (int b = 0; b < 8; ++b) {
            const float l = lfin[b][0], c = lfin[b][1], u = lfin[b][2];
            if (c > 0.f) { per += l / fmaxf(c, 1.f); nv += 1.f; }
            uc += u;
        }
        const float loss_sup = (scn > 0.f) ? ssum / fmaxf(scn, 1.f) : 0.f;
        float lgr = per / fmaxf(nv, 1.f);
        if (!(uc > 0.f)) lgr = 0.f;
        out[0] = loss_sup + GRAPH_WEIGHT * lgr;
    }
}

extern "C" void kernel_launch(void* const* d_in, const int* in_sizes, int n_in,
                              void* d_out, int out_size, void* d_ws, size_t ws_size,
                              hipStream_t stream) {
    const v4f* lg4 = (const v4f*)d_in[0];  // logits  [B,N,1]
    const v4f* tg4 = (const v4f*)d_in[1];  // targets [B,N]
    const v4i* sm4 = (const v4i*)d_in[2];  // sup_mask (int32)
    const v4i* im4 = (const v4i*)d_in[3];  // ignore_mask (int32)
    const v4i* kvi4 = (const v4i*)d_in[4]; // kv_indices [B,NB,MAXKV]
    const int* kvn  = (const int*)d_in[5]; // kv_num_blocks [B,NB]
    float* ws  = (float*)d_ws;
    float* out = (float*)d_out;

    // 3 dispatches total; no memset (all ws slots fully overwritten), no atomics.
    k_phase1<<<P1_WGS, 256, 0, stream>>>(lg4, tg4, sm4, im4, ws);
    k_phase2<<<P2_WGS, 256, 0, stream>>>(kvi4, kvn, ws);
    k_phase3<<<1, 1024, 0, stream>>>(ws, out);
}

// Round 5
// 164.077 us; speedup vs baseline: 1.2271x; 1.0465x over previous
//
#include <hip/hip_runtime.h>

// Problem constants (fixed by setup_inputs)
constexpr int BATCH = 8;
constexpr int NPB   = 1 << 20;       // N per batch
constexpr int BS    = 128;           // block_size
constexpr int NB    = NPB / BS;      // 8192 node-blocks per batch
constexpr int NBLK  = BATCH * NB;    // 65536 total node-blocks
constexpr int MAXKV = 32;

#define GRAPH_WEIGHT 0.3f

constexpr int P1_WGS = (BATCH * NPB) / (256 * 8);  // 4096 wgs, 8 elems/thread
constexpr int P2_WGS = 2048;                        // 32 node-blocks per wg

// Workspace layout (floats). Every slot fully overwritten each call ->
// no memset dispatch, no atomics anywhere.
constexpr int WS_BSC = 0;                    // float2[NBLK] {sum keep*p, keep cnt}
constexpr int WS_QUP = 2 * NBLK;             // float4[NBLK] {q, sum u*p, sum u*p^2, 0}
constexpr int WS_SUP = WS_QUP + 4 * NBLK;    // float2[P1_WGS] {sup_sum, sup_cnt}
constexpr int WS_P2  = WS_SUP + 2 * P1_WGS;  // float4[P2_WGS] {L, C, U, 0}

typedef float v4f __attribute__((ext_vector_type(4)));
typedef int   v4i __attribute__((ext_vector_type(4)));

// ---------------- Phase 1: per-element pass + per-block stats ----------------
// (unchanged from R4 — proven ~<41us) 8 elems/thread, nontemporal 16B loads,
// one wave = 512 elements = 4 node-blocks; lanes 16g..16g+15 own block g.
__global__ __launch_bounds__(256) void k_phase1(const v4f* __restrict__ lg4,
                                                const v4f* __restrict__ tg4,
                                                const v4i* __restrict__ sm4,
                                                const v4i* __restrict__ im4,
                                                float* __restrict__ ws)
{
    const int lane = threadIdx.x & 63;
    const int wid  = (blockIdx.x << 2) + (threadIdx.x >> 6); // global wave id
    const int grp  = lane >> 4;                  // block within wave (0..3)
    const int sub  = lane & 15;                  // sub-lane within block group
    const int blk  = (wid << 2) + grp;           // node-block id (0..NBLK-1)
    const int c0   = (blk << 5) + sub;           // float4-chunk index (32/block)

    v4f xv[2], tv[2];
    v4i sv[2], gv[2];
    xv[0] = __builtin_nontemporal_load(lg4 + c0);
    xv[1] = __builtin_nontemporal_load(lg4 + c0 + 16);
    tv[0] = __builtin_nontemporal_load(tg4 + c0);
    tv[1] = __builtin_nontemporal_load(tg4 + c0 + 16);
    sv[0] = __builtin_nontemporal_load(sm4 + c0);
    sv[1] = __builtin_nontemporal_load(sm4 + c0 + 16);
    gv[0] = __builtin_nontemporal_load(im4 + c0);
    gv[1] = __builtin_nontemporal_load(im4 + c0 + 16);

    float sup_sum = 0.f, sup_cnt = 0.f;
    float bsum = 0.f, bcnt = 0.f, q = 0.f, up = 0.f, up2 = 0.f;

#pragma unroll
    for (int j = 0; j < 2; ++j) {
#pragma unroll
        for (int k = 0; k < 4; ++k) {
            const float x = xv[j][k], t = tv[j][k];
            const bool s = (sv[j][k] != 0);
            const bool g = (gv[j][k] != 0);

            const float ax  = fabsf(x);
            const float e   = __expf(-ax);          // (0,1]
            const float lp  = __logf(1.f + e);      // log1p(exp(-|x|))
            const float per = fmaxf(x, 0.f) - x * t + lp;
            const float inv = 1.f / (1.f + e);
            const float p   = (x >= 0.f) ? inv : e * inv;   // sigmoid(x)

            if (s) { sup_sum += per; sup_cnt += 1.f; }
            if (!g) { bsum += p; bcnt += 1.f; }
            if (!g && !s) { q += 1.f; up += p; up2 += p * p; }
        }
    }

    // block stats: reduce over the 16-lane group (d = 8,4,2,1)
#pragma unroll
    for (int d = 8; d >= 1; d >>= 1) {
        bsum += __shfl_xor(bsum, d);
        bcnt += __shfl_xor(bcnt, d);
        q    += __shfl_xor(q, d);
        up   += __shfl_xor(up, d);
        up2  += __shfl_xor(up2, d);
    }
    if (sub == 0) {
        *reinterpret_cast<float2*>(ws + WS_BSC + 2 * blk) = make_float2(bsum, bcnt);
        *reinterpret_cast<float4*>(ws + WS_QUP + 4 * blk) = make_float4(q, up, up2, 0.f);
    }

    // sup terms: full-wave reduction, one plain float2 store per workgroup
#pragma unroll
    for (int d = 32; d >= 1; d >>= 1) {
        sup_sum += __shfl_xor(sup_sum, d);
        sup_cnt += __shfl_xor(sup_cnt, d);
    }
    __shared__ float lsup[4][2];
    const int w = threadIdx.x >> 6;
    if (lane == 0) { lsup[w][0] = sup_sum; lsup[w][1] = sup_cnt; }
    __syncthreads();
    if (threadIdx.x == 0) {
        const float a = lsup[0][0] + lsup[1][0] + lsup[2][0] + lsup[3][0];
        const float b = lsup[0][1] + lsup[1][1] + lsup[2][1] + lsup[3][1];
        *reinterpret_cast<float2*>(ws + WS_SUP + 2 * blockIdx.x) = make_float2(a, b);
    }
}

// ---------------- Phase 2: neighbor gather, 32 node-blocks per wg ----------
// Each 32-lane half-wave handles 4 consecutive node-blocks in one pass:
// int4 kvn load, 4 upfront coalesced idx loads, 4 gather rounds (all 32 lanes),
// then lanes 0..3 finish one block each (coalesced 64B QUP read) and a 2-stage
// reduce. One float4 partial per wg (2048 total) -> phase3 reads only 64KB.
__global__ __launch_bounds__(256) void k_phase2(const int* __restrict__ kvi,
                                                const int* __restrict__ kvn,
                                                float* __restrict__ ws)
{
    const int hw     = threadIdx.x >> 5;        // half-wave 0..7
    const int lane32 = threadIdx.x & 31;
    const int h0     = blockIdx.x * 32 + hw * 4;          // first of 4 blocks
    const int bbase  = (blockIdx.x >> 8) << 13;           // batch * NB

    const v4i nkv4 = *reinterpret_cast<const v4i*>(kvn + h0);

    int idxs[4];
#pragma unroll
    for (int j = 0; j < 4; ++j)
        idxs[j] = __builtin_nontemporal_load(kvi + (size_t)(h0 + j) * MAXKV + lane32);

    float gsv[4], gcv[4];
#pragma unroll
    for (int j = 0; j < 4; ++j) {
        float gs = 0.f, gc = 0.f;
        if (lane32 < nkv4[j]) {
            const float2 v = *reinterpret_cast<const float2*>(ws + WS_BSC + 2 * (bbase + idxs[j]));
            gs = v.x; gc = v.y;
        }
#pragma unroll
        for (int d = 16; d >= 1; d >>= 1) {
            gs += __shfl_xor(gs, d);
            gc += __shfl_xor(gc, d);
        }
        gsv[j] = gs; gcv[j] = gc;   // every lane now holds block j's totals
    }

    // lanes 0..3: finalize block h0+lane (coalesced 64B QUP read)
    float L = 0.f, C = 0.f, U = 0.f;
    if (lane32 < 4) {
        const int k = lane32;
        const float4 quv = *reinterpret_cast<const float4*>(ws + WS_QUP + 4 * (h0 + k));
        const float q = quv.x, up = quv.y, up2 = quv.z;
        const float gs = gsv[k], gc = gcv[k];
        const float m  = gs / fmaxf(gc, 1.f);
        const bool  vb = (q > 0.f) && (nkv4[k] > 0) && (gc > 0.f);
        const float sq = up2 - 2.f * m * up + m * m * q;  // sum_u (p-m)^2
        L = vb ? sq : 0.f;
        C = vb ? q  : 0.f;
        U = q;                                   // unconditional: uncertain.any()
    }
#pragma unroll
    for (int d = 2; d >= 1; d >>= 1) {
        L += __shfl_xor(L, d);
        C += __shfl_xor(C, d);
        U += __shfl_xor(U, d);
    }

    __shared__ float l2s[8][3];
    if (lane32 == 0) { l2s[hw][0] = L; l2s[hw][1] = C; l2s[hw][2] = U; }
    __syncthreads();
    if (threadIdx.x == 0) {
        float Ls = 0.f, Cs = 0.f, Us = 0.f;
#pragma unroll
        for (int j = 0; j < 8; ++j) { Ls += l2s[j][0]; Cs += l2s[j][1]; Us += l2s[j][2]; }
        *reinterpret_cast<float4*>(ws + WS_P2 + 4 * blockIdx.x) = make_float4(Ls, Cs, Us, 0.f);
    }
}

// ---------------- Phase 3: final reduce (one 512-thread workgroup) ----------
// Reads 2048 float4 sup-partials-as-float4 (32KB) + 2048 float4 p2 partials
// (32KB). Wave b owns batch b's 256 p2 slots.
__global__ __launch_bounds__(512) void k_phase3(const float* __restrict__ ws,
                                                float* __restrict__ out)
{
    const int tid  = threadIdx.x;          // 0..511
    const int lane = tid & 63;
    const int w    = tid >> 6;             // wave 0..7

    __shared__ float lsup[8][2];
    __shared__ float lfin[8][3];

    // sup partials: 4096 float2 = 2048 float4 {s0,c0,s1,c1}; 4 float4/thread
    const v4f* supf4 = reinterpret_cast<const v4f*>(ws + WS_SUP);
    float ss = 0.f, sc = 0.f;
#pragma unroll
    for (int j = 0; j < 4; ++j) {
        const v4f v = __builtin_nontemporal_load(supf4 + tid * 4 + j);
        ss += v.x + v.z; sc += v.y + v.w;
    }
#pragma unroll
    for (int d = 32; d >= 1; d >>= 1) { ss += __shfl_xor(ss, d); sc += __shfl_xor(sc, d); }
    if (lane == 0) { lsup[w][0] = ss; lsup[w][1] = sc; }

    // p2 partials: wave w handles batch w: slots [w*256, w*256+256), 4/lane
    const v4f* p2f4 = reinterpret_cast<const v4f*>(ws + WS_P2);
    float L = 0.f, C = 0.f, U = 0.f;
#pragma unroll
    for (int j = 0; j < 4; ++j) {
        const v4f v = __builtin_nontemporal_load(p2f4 + w * 256 + lane * 4 + j);
        L += v.x; C += v.y; U += v.z;
    }
#pragma unroll
    for (int d = 32; d >= 1; d >>= 1) {
        L += __shfl_xor(L, d);
        C += __shfl_xor(C, d);
        U += __shfl_xor(U, d);
    }
    if (lane == 0) { lfin[w][0] = L; lfin[w][1] = C; lfin[w][2] = U; }
    __syncthreads();

    if (tid == 0) {
        float ssum = 0.f, scn = 0.f;
#pragma unroll
        for (int j = 0; j < 8; ++j) { ssum += lsup[j][0]; scn += lsup[j][1]; }
        float per = 0.f, nv = 0.f, uc = 0.f;
#pragma unroll
        for (int b = 0; b < 8; ++b) {
            const float l = lfin[b][0], c = lfin[b][1], u = lfin[b][2];
            if (c > 0.f) { per += l / fmaxf(c, 1.f); nv += 1.f; }
            uc += u;
        }
        const float loss_sup = (scn > 0.f) ? ssum / fmaxf(scn, 1.f) : 0.f;
        float lgr = per / fmaxf(nv, 1.f);
        if (!(uc > 0.f)) lgr = 0.f;
        out[0] = loss_sup + GRAPH_WEIGHT * lgr;
    }
}

extern "C" void kernel_launch(void* const* d_in, const int* in_sizes, int n_in,
                              void* d_out, int out_size, void* d_ws, size_t ws_size,
                              hipStream_t stream) {
    const v4f* lg4 = (const v4f*)d_in[0];  // logits  [B,N,1]
    const v4f* tg4 = (const v4f*)d_in[1];  // targets [B,N]
    const v4i* sm4 = (const v4i*)d_in[2];  // sup_mask (int32)
    const v4i* im4 = (const v4i*)d_in[3];  // ignore_mask (int32)
    const int* kvi = (const int*)d_in[4];  // kv_indices [B,NB,MAXKV]
    const int* kvn = (const int*)d_in[5];  // kv_num_blocks [B,NB]
    float* ws  = (float*)d_ws;
    float* out = (float*)d_out;

    k_phase1<<<P1_WGS, 256, 0, stream>>>(lg4, tg4, sm4, im4, ws);
    k_phase2<<<P2_WGS, 256, 0, stream>>>(kvi, kvn, ws);
    k_phase3<<<1, 512, 0, stream>>>(ws, out);
}